// Round 9
// baseline (224.096 us; speedup 1.0000x reference)
//
#include <hip/hip_runtime.h>

// TAGConv: N=50000, E=800000, F=64, OUT=64, K=3.
// Round 9: fuse the output GEMM into the spmm epilogues. Each 16-lane
// row-group ends spmm holding the full h-row in registers; __shfl(.,k4,16)
// broadcasts + W-chunk in LDS turn that into out[r] += h@W_s on the spot.
// h3 is never materialized; the standalone GEMM kernel is deleted.

#define F 64
#define OUT 64
#define SCAN_ELEMS 1024
#define NPART 8

__global__ __launch_bounds__(256) void count_part(
    const int* __restrict__ row, int* __restrict__ counts, int E, int rpp) {
  int part = blockIdx.x & (NPART - 1);
  int e = (blockIdx.x >> 3) * 256 + threadIdx.x;
  if (e >= E) return;
  int r = row[e];
  if ((unsigned)(r - part * rpp) >= (unsigned)rpp) return;
  atomicAdd(&counts[r], 1);
}

__global__ __launch_bounds__(256) void block_scan(
    const int* __restrict__ counts, int* __restrict__ offsets,
    int* __restrict__ blockSums, int N) {
  __shared__ int s[256];
  int t = threadIdx.x;
  int base = blockIdx.x * SCAN_ELEMS + t * 4;
  int v0 = 0, v1 = 0, v2 = 0, v3 = 0;
  if (base + 3 < N) {
    int4 c = *(const int4*)&counts[base];
    v0 = c.x; v1 = c.y; v2 = c.z; v3 = c.w;
  } else {
    if (base < N)     v0 = counts[base];
    if (base + 1 < N) v1 = counts[base + 1];
    if (base + 2 < N) v2 = counts[base + 2];
  }
  s[t] = v0 + v1 + v2 + v3;
  __syncthreads();
  for (int d = 1; d < 256; d <<= 1) {
    int x = (t >= d) ? s[t - d] : 0;
    __syncthreads();
    s[t] += x;
    __syncthreads();
  }
  int ex = (t == 0) ? 0 : s[t - 1];
  if (t == 255) blockSums[blockIdx.x] = s[255];
  int o0 = ex, o1 = o0 + v0, o2 = o1 + v1, o3 = o2 + v2;
  if (base + 3 < N) {
    *(int4*)&offsets[base] = make_int4(o0, o1, o2, o3);
  } else {
    if (base < N)     offsets[base]     = o0;
    if (base + 1 < N) offsets[base + 1] = o1;
    if (base + 2 < N) offsets[base + 2] = o2;
  }
}

__global__ __launch_bounds__(64) void scan_sums(int* __restrict__ blockSums, int nb) {
  int lane = threadIdx.x;
  if (nb <= 64) {
    int v = (lane < nb) ? blockSums[lane] : 0;
    int incl = v;
    for (int d = 1; d < 64; d <<= 1) {
      int u = __shfl_up(incl, d, 64);
      if (lane >= d) incl += u;
    }
    if (lane < nb) blockSums[lane] = incl - v;
  } else if (lane == 0) {
    int run = 0;
    for (int i = 0; i < nb; ++i) { int c = blockSums[i]; blockSums[i] = run; run += c; }
  }
}

__global__ __launch_bounds__(256) void add_offsets(
    int* __restrict__ offsets, const int* __restrict__ blockSums,
    int* __restrict__ cursor, int N, int E) {
  int i = blockIdx.x * 256 + threadIdx.x;
  if (i < N) {
    int o = offsets[i] + blockSums[i >> 10];
    offsets[i] = o;
    cursor[i] = o;
  }
  if (i == 0) offsets[N] = E;
}

__global__ __launch_bounds__(256) void scatter_part(
    const int* __restrict__ row, const int* __restrict__ col,
    const float* __restrict__ val, int* __restrict__ cursor,
    float2* __restrict__ recs, int E, int rpp) {
  int part = blockIdx.x & (NPART - 1);
  int e = (blockIdx.x >> 3) * 256 + threadIdx.x;
  if (e >= E) return;
  int r = row[e];
  unsigned lo = (unsigned)(part * rpp);
  if ((unsigned)(r - lo) >= (unsigned)rpp) return;
  int p = atomicAdd(&cursor[r], 1);
  recs[p] = make_float2(__int_as_float(col[e]), val[e]);
}

// Shared gather body: 16-lane group per row, lane owns features fp..fp+3.
__device__ __forceinline__ float4 gather_row(
    const int* __restrict__ off, const float2* __restrict__ recs,
    const float* __restrict__ hin, int r, int fp) {
  int i = off[r], end = off[r + 1];
  float4 acc = make_float4(0.f, 0.f, 0.f, 0.f);
  for (; i + 4 <= end; i += 4) {
    float2 e0 = recs[i], e1 = recs[i + 1], e2 = recs[i + 2], e3 = recs[i + 3];
    float4 h0 = *(const float4*)&hin[(size_t)__float_as_int(e0.x) * F + fp];
    float4 h1 = *(const float4*)&hin[(size_t)__float_as_int(e1.x) * F + fp];
    float4 h2 = *(const float4*)&hin[(size_t)__float_as_int(e2.x) * F + fp];
    float4 h3 = *(const float4*)&hin[(size_t)__float_as_int(e3.x) * F + fp];
    acc.x = fmaf(e0.y, h0.x, acc.x); acc.y = fmaf(e0.y, h0.y, acc.y);
    acc.z = fmaf(e0.y, h0.z, acc.z); acc.w = fmaf(e0.y, h0.w, acc.w);
    acc.x = fmaf(e1.y, h1.x, acc.x); acc.y = fmaf(e1.y, h1.y, acc.y);
    acc.z = fmaf(e1.y, h1.z, acc.z); acc.w = fmaf(e1.y, h1.w, acc.w);
    acc.x = fmaf(e2.y, h2.x, acc.x); acc.y = fmaf(e2.y, h2.y, acc.y);
    acc.z = fmaf(e2.y, h2.z, acc.z); acc.w = fmaf(e2.y, h2.w, acc.w);
    acc.x = fmaf(e3.y, h3.x, acc.x); acc.y = fmaf(e3.y, h3.y, acc.y);
    acc.z = fmaf(e3.y, h3.z, acc.z); acc.w = fmaf(e3.y, h3.w, acc.w);
  }
  for (; i < end; ++i) {
    float2 e0 = recs[i];
    float4 h0 = *(const float4*)&hin[(size_t)__float_as_int(e0.x) * F + fp];
    acc.x = fmaf(e0.y, h0.x, acc.x); acc.y = fmaf(e0.y, h0.y, acc.y);
    acc.z = fmaf(e0.y, h0.z, acc.z); acc.w = fmaf(e0.y, h0.w, acc.w);
  }
  return acc;
}

// acc-row (held across the 16-lane group) @ W-chunk (LDS) -> oa (lane's 4 outs).
__device__ __forceinline__ void row_times_W(
    float4 hrow, const float* __restrict__ Wl, int fp, float4& oa) {
#pragma unroll
  for (int k4 = 0; k4 < 16; ++k4) {
    float hx = __shfl(hrow.x, k4, 16);
    float hy = __shfl(hrow.y, k4, 16);
    float hz = __shfl(hrow.z, k4, 16);
    float hw = __shfl(hrow.w, k4, 16);
    float4 w0 = *(const float4*)&Wl[(k4 * 4 + 0) * 64 + fp];
    float4 w1 = *(const float4*)&Wl[(k4 * 4 + 1) * 64 + fp];
    float4 w2 = *(const float4*)&Wl[(k4 * 4 + 2) * 64 + fp];
    float4 w3 = *(const float4*)&Wl[(k4 * 4 + 3) * 64 + fp];
    oa.x = fmaf(hx, w0.x, oa.x); oa.y = fmaf(hx, w0.y, oa.y);
    oa.z = fmaf(hx, w0.z, oa.z); oa.w = fmaf(hx, w0.w, oa.w);
    oa.x = fmaf(hy, w1.x, oa.x); oa.y = fmaf(hy, w1.y, oa.y);
    oa.z = fmaf(hy, w1.z, oa.z); oa.w = fmaf(hy, w1.w, oa.w);
    oa.x = fmaf(hz, w2.x, oa.x); oa.y = fmaf(hz, w2.y, oa.y);
    oa.z = fmaf(hz, w2.z, oa.z); oa.w = fmaf(hz, w2.w, oa.w);
    oa.x = fmaf(hw, w3.x, oa.x); oa.y = fmaf(hw, w3.y, oa.y);
    oa.z = fmaf(hw, w3.z, oa.z); oa.w = fmaf(hw, w3.w, oa.w);
  }
}

// Stage 1: h1 = A x (write h1); out = bias + x@W0 + h1@W1.
__global__ __launch_bounds__(256) void spmm_gemm1(
    const int* __restrict__ off, const float2* __restrict__ recs,
    const float* __restrict__ x, float* __restrict__ h1,
    const float* __restrict__ W, const float* __restrict__ bias,
    float* __restrict__ out, int N) {
  __shared__ float Wl[2 * 4096];  // W0, W1
  int t = threadIdx.x;
#pragma unroll
  for (int i = 0; i < 8; ++i)
    ((float4*)Wl)[t + i * 256] = ((const float4*)W)[t + i * 256];
  __syncthreads();

  int r = (blockIdx.x * 256 + t) >> 4;
  if (r >= N) return;
  int fp = (t & 15) << 2;

  float4 acc = gather_row(off, recs, x, r, fp);
  *(float4*)&h1[(size_t)r * F + fp] = acc;

  float4 xv = *(const float4*)&x[(size_t)r * F + fp];
  float4 oa = ((const float4*)bias)[t & 15];
  row_times_W(xv, Wl, fp, oa);
  row_times_W(acc, Wl + 4096, fp, oa);
  *(float4*)&out[(size_t)r * OUT + fp] = oa;
}

// Stage 2: h2 = A h1 (write h2); out += h2@W2.
__global__ __launch_bounds__(256) void spmm_gemm2(
    const int* __restrict__ off, const float2* __restrict__ recs,
    const float* __restrict__ h1, float* __restrict__ h2,
    const float* __restrict__ W2, float* __restrict__ out, int N) {
  __shared__ float Wl[4096];
  int t = threadIdx.x;
#pragma unroll
  for (int i = 0; i < 4; ++i)
    ((float4*)Wl)[t + i * 256] = ((const float4*)W2)[t + i * 256];
  __syncthreads();

  int r = (blockIdx.x * 256 + t) >> 4;
  if (r >= N) return;
  int fp = (t & 15) << 2;

  float4 acc = gather_row(off, recs, h1, r, fp);
  *(float4*)&h2[(size_t)r * F + fp] = acc;

  float4 oa = *(const float4*)&out[(size_t)r * OUT + fp];
  row_times_W(acc, Wl, fp, oa);
  *(float4*)&out[(size_t)r * OUT + fp] = oa;
}

// Stage 3: h3 = A h2 (registers only); out += h3@W3.
__global__ __launch_bounds__(256) void spmm_gemm3(
    const int* __restrict__ off, const float2* __restrict__ recs,
    const float* __restrict__ h2, const float* __restrict__ W3,
    float* __restrict__ out, int N) {
  __shared__ float Wl[4096];
  int t = threadIdx.x;
#pragma unroll
  for (int i = 0; i < 4; ++i)
    ((float4*)Wl)[t + i * 256] = ((const float4*)W3)[t + i * 256];
  __syncthreads();

  int r = (blockIdx.x * 256 + t) >> 4;
  if (r >= N) return;
  int fp = (t & 15) << 2;

  float4 acc = gather_row(off, recs, h2, r, fp);

  float4 oa = *(const float4*)&out[(size_t)r * OUT + fp];
  row_times_W(acc, Wl, fp, oa);
  *(float4*)&out[(size_t)r * OUT + fp] = oa;
}

extern "C" void kernel_launch(void* const* d_in, const int* in_sizes, int n_in,
                              void* d_out, int out_size, void* d_ws, size_t ws_size,
                              hipStream_t stream) {
  const float* x    = (const float*)d_in[0];
  const int*   erow = (const int*)d_in[1];
  const int*   ecol = (const int*)d_in[2];
  const float* eval = (const float*)d_in[3];
  const float* W    = (const float*)d_in[4];
  const float* b    = (const float*)d_in[5];
  float* out = (float*)d_out;

  int N = in_sizes[0] / F;
  int E = in_sizes[1];
  size_t SZ = (size_t)N * F * sizeof(float);
  int nScanBlocks = (N + SCAN_ELEMS - 1) / SCAN_ELEMS;
  int rpp = (N + NPART - 1) / NPART;

  char* p = (char*)d_ws;
  float*  hA     = (float*)p;  p += SZ;
  float*  hB     = (float*)p;  p += SZ;
  float2* recs   = (float2*)p; p += (size_t)E * sizeof(float2);
  int*    counts = (int*)p;    p += (size_t)N * sizeof(int);
  int*    offs   = (int*)p;    p += (size_t)(N + 1) * sizeof(int);
  int*    cursor = (int*)p;    p += (size_t)N * sizeof(int);
  int*    bsums  = (int*)p;    p += (size_t)nScanBlocks * sizeof(int);

  int egrid = (E + 255) / 256;
  int g16grid = ((size_t)N * 16 + 255) / 256;

  // --- CSR build ---
  hipMemsetAsync(counts, 0, (size_t)N * sizeof(int), stream);
  count_part<<<egrid * NPART, 256, 0, stream>>>(erow, counts, E, rpp);
  block_scan<<<nScanBlocks, 256, 0, stream>>>(counts, offs, bsums, N);
  scan_sums<<<1, 64, 0, stream>>>(bsums, nScanBlocks);
  add_offsets<<<(N + 255) / 256, 256, 0, stream>>>(offs, bsums, cursor, N, E);
  scatter_part<<<egrid * NPART, 256, 0, stream>>>(erow, ecol, eval, cursor, recs, E, rpp);

  // --- fused propagation + projection ---
  spmm_gemm1<<<g16grid, 256, 0, stream>>>(offs, recs, x, hA, W, b, out, N);
  spmm_gemm2<<<g16grid, 256, 0, stream>>>(offs, recs, hA, hB, W + 2 * 4096, out, N);
  spmm_gemm3<<<g16grid, 256, 0, stream>>>(offs, recs, hB, W + 3 * 4096, out, N);
}

// Round 10
// 202.836 us; speedup vs baseline: 1.1048x; 1.1048x over previous
//
#include <hip/hip_runtime.h>

// TAGConv: N=50000, E=800000, F=64, OUT=64, K=3.
// Round 10: col-bucketed CSR (edges sorted by (row, col>>13)) so concurrent
// waves gather from the same 2MB h-window -> L2/L3 hits instead of HBM.
// Split structure restored; gemm v5 = 2 nodes/thread, 391 blocks.

#define F 64
#define OUT 64
#define SCAN_ELEMS 1024
#define NPART 8
#define CB_SHIFT 13  // col-block = 8192 nodes = 2MB of h

__global__ __launch_bounds__(256) void count_part(
    const int* __restrict__ row, const int* __restrict__ col,
    int* __restrict__ counts, int E, int rpp, int ncb) {
  int part = blockIdx.x & (NPART - 1);
  int e = (blockIdx.x >> 3) * 256 + threadIdx.x;
  if (e >= E) return;
  int r = row[e];
  if ((unsigned)(r - part * rpp) >= (unsigned)rpp) return;
  atomicAdd(&counts[r * ncb + (col[e] >> CB_SHIFT)], 1);
}

__global__ __launch_bounds__(256) void block_scan(
    const int* __restrict__ counts, int* __restrict__ offsets,
    int* __restrict__ blockSums, int B) {
  __shared__ int s[256];
  int t = threadIdx.x;
  int base = blockIdx.x * SCAN_ELEMS + t * 4;
  int v0 = 0, v1 = 0, v2 = 0, v3 = 0;
  if (base + 3 < B) {
    int4 c = *(const int4*)&counts[base];
    v0 = c.x; v1 = c.y; v2 = c.z; v3 = c.w;
  } else {
    if (base < B)     v0 = counts[base];
    if (base + 1 < B) v1 = counts[base + 1];
    if (base + 2 < B) v2 = counts[base + 2];
  }
  s[t] = v0 + v1 + v2 + v3;
  __syncthreads();
  for (int d = 1; d < 256; d <<= 1) {
    int x = (t >= d) ? s[t - d] : 0;
    __syncthreads();
    s[t] += x;
    __syncthreads();
  }
  int ex = (t == 0) ? 0 : s[t - 1];
  if (t == 255) blockSums[blockIdx.x] = s[255];
  int o0 = ex, o1 = o0 + v0, o2 = o1 + v1, o3 = o2 + v2;
  if (base + 3 < B) {
    *(int4*)&offsets[base] = make_int4(o0, o1, o2, o3);
  } else {
    if (base < B)     offsets[base]     = o0;
    if (base + 1 < B) offsets[base + 1] = o1;
    if (base + 2 < B) offsets[base + 2] = o2;
  }
}

// Chunked exclusive scan of blockSums (nb up to 64*chunk), one 64-lane wave.
__global__ __launch_bounds__(64) void scan_sums(int* __restrict__ bs, int nb) {
  int lane = threadIdx.x;
  int chunk = (nb + 63) / 64;
  int b = lane * chunk, e = min(b + chunk, nb);
  int sum = 0;
  for (int i = b; i < e; ++i) sum += bs[i];
  int incl = sum;
  for (int d = 1; d < 64; d <<= 1) {
    int u = __shfl_up(incl, d, 64);
    if (lane >= d) incl += u;
  }
  int run = incl - sum;
  for (int i = b; i < e; ++i) { int c = bs[i]; bs[i] = run; run += c; }
}

__global__ __launch_bounds__(256) void add_offsets(
    int* __restrict__ offsets, const int* __restrict__ blockSums,
    int* __restrict__ cursor, int B, int E) {
  int i = blockIdx.x * 256 + threadIdx.x;
  if (i < B) {
    int o = offsets[i] + blockSums[i >> 10];
    offsets[i] = o;
    cursor[i] = o;
  }
  if (i == 0) offsets[B] = E;
}

__global__ __launch_bounds__(256) void scatter_part(
    const int* __restrict__ row, const int* __restrict__ col,
    const float* __restrict__ val, int* __restrict__ cursor,
    float2* __restrict__ recs, int E, int rpp, int ncb) {
  int part = blockIdx.x & (NPART - 1);
  int e = (blockIdx.x >> 3) * 256 + threadIdx.x;
  if (e >= E) return;
  int r = row[e];
  if ((unsigned)(r - part * rpp) >= (unsigned)rpp) return;
  int c = col[e];
  int p = atomicAdd(&cursor[r * ncb + (c >> CB_SHIFT)], 1);
  recs[p] = make_float2(__int_as_float(c), val[e]);
}

// 16-lane group per row; lane owns 4 features. Edges are col-block sorted.
__global__ __launch_bounds__(256) void spmm_g16(
    const int* __restrict__ off, const float2* __restrict__ recs,
    const float* __restrict__ hin, float* __restrict__ hout, int N, int ncb) {
  int r = (blockIdx.x * 256 + threadIdx.x) >> 4;
  if (r >= N) return;
  int fp = (threadIdx.x & 15) << 2;
  int i = off[r * ncb], end = off[r * ncb + ncb];
  float4 acc = make_float4(0.f, 0.f, 0.f, 0.f);

  for (; i + 4 <= end; i += 4) {
    float2 e0 = recs[i], e1 = recs[i + 1], e2 = recs[i + 2], e3 = recs[i + 3];
    float4 h0 = *(const float4*)&hin[(size_t)__float_as_int(e0.x) * F + fp];
    float4 h1 = *(const float4*)&hin[(size_t)__float_as_int(e1.x) * F + fp];
    float4 h2 = *(const float4*)&hin[(size_t)__float_as_int(e2.x) * F + fp];
    float4 h3 = *(const float4*)&hin[(size_t)__float_as_int(e3.x) * F + fp];
    acc.x = fmaf(e0.y, h0.x, acc.x); acc.y = fmaf(e0.y, h0.y, acc.y);
    acc.z = fmaf(e0.y, h0.z, acc.z); acc.w = fmaf(e0.y, h0.w, acc.w);
    acc.x = fmaf(e1.y, h1.x, acc.x); acc.y = fmaf(e1.y, h1.y, acc.y);
    acc.z = fmaf(e1.y, h1.z, acc.z); acc.w = fmaf(e1.y, h1.w, acc.w);
    acc.x = fmaf(e2.y, h2.x, acc.x); acc.y = fmaf(e2.y, h2.y, acc.y);
    acc.z = fmaf(e2.y, h2.z, acc.z); acc.w = fmaf(e2.y, h2.w, acc.w);
    acc.x = fmaf(e3.y, h3.x, acc.x); acc.y = fmaf(e3.y, h3.y, acc.y);
    acc.z = fmaf(e3.y, h3.z, acc.z); acc.w = fmaf(e3.y, h3.w, acc.w);
  }
  for (; i < end; ++i) {
    float2 e0 = recs[i];
    float4 h0 = *(const float4*)&hin[(size_t)__float_as_int(e0.x) * F + fp];
    acc.x = fmaf(e0.y, h0.x, acc.x); acc.y = fmaf(e0.y, h0.y, acc.y);
    acc.z = fmaf(e0.y, h0.z, acc.z); acc.w = fmaf(e0.y, h0.w, acc.w);
  }
  *(float4*)&hout[(size_t)r * F + fp] = acc;
}

// out = bias + h0@W0 + h1@W1 + h2@W2 + h3@W3 (h3 lives in out).
// Thread = 2 nodes x 16 outs; block = 128 nodes; grid 391 (2x v4's waves).
__global__ __launch_bounds__(256) void gemm_fused4_v5(
    const float* __restrict__ h0, const float* __restrict__ h1,
    const float* __restrict__ h2, const float* __restrict__ W,
    const float* __restrict__ bias, float* __restrict__ out, int N) {
  __shared__ float Ws[64 * 64];
  const float* hs[4] = {h0, h1, h2, out};

  int t = threadIdx.x;
  int oq = t & 3;
  int og = oq << 4;
  int ns = t >> 2;
  int node0 = blockIdx.x * 128;
  int n0 = min(node0 + ns, N - 1);
  int n1 = min(node0 + ns + 64, N - 1);

  const float4* b4 = (const float4*)bias;
  float4 acc[2][4];
#pragma unroll
  for (int m = 0; m < 4; ++m) { acc[0][m] = b4[oq * 4 + m]; acc[1][m] = acc[0][m]; }

#pragma unroll
  for (int s = 0; s < 4; ++s) {
    __syncthreads();
    const float4* Wg = (const float4*)(W + s * 4096);
#pragma unroll
    for (int i = 0; i < 4; ++i) ((float4*)Ws)[t + i * 256] = Wg[t + i * 256];
    __syncthreads();

    const float4* hr0 = (const float4*)(hs[s] + (size_t)n0 * F);
    const float4* hr1 = (const float4*)(hs[s] + (size_t)n1 * F);
    float4 hc0 = hr0[0], hc1 = hr1[0], hn0, hn1;

#pragma unroll 2
    for (int k4 = 0; k4 < 16; ++k4) {
      if (k4 < 15) { hn0 = hr0[k4 + 1]; hn1 = hr1[k4 + 1]; }
#pragma unroll
      for (int j = 0; j < 4; ++j) {
        const float4* w4 = (const float4*)&Ws[(k4 * 4 + j) * 64 + og];
        float4 w0 = w4[0], w1 = w4[1], w2 = w4[2], w3 = w4[3];
        float a = (j == 0) ? hc0.x : (j == 1) ? hc0.y : (j == 2) ? hc0.z : hc0.w;
        float c = (j == 0) ? hc1.x : (j == 1) ? hc1.y : (j == 2) ? hc1.z : hc1.w;
        acc[0][0].x = fmaf(a, w0.x, acc[0][0].x); acc[0][0].y = fmaf(a, w0.y, acc[0][0].y);
        acc[0][0].z = fmaf(a, w0.z, acc[0][0].z); acc[0][0].w = fmaf(a, w0.w, acc[0][0].w);
        acc[0][1].x = fmaf(a, w1.x, acc[0][1].x); acc[0][1].y = fmaf(a, w1.y, acc[0][1].y);
        acc[0][1].z = fmaf(a, w1.z, acc[0][1].z); acc[0][1].w = fmaf(a, w1.w, acc[0][1].w);
        acc[0][2].x = fmaf(a, w2.x, acc[0][2].x); acc[0][2].y = fmaf(a, w2.y, acc[0][2].y);
        acc[0][2].z = fmaf(a, w2.z, acc[0][2].z); acc[0][2].w = fmaf(a, w2.w, acc[0][2].w);
        acc[0][3].x = fmaf(a, w3.x, acc[0][3].x); acc[0][3].y = fmaf(a, w3.y, acc[0][3].y);
        acc[0][3].z = fmaf(a, w3.z, acc[0][3].z); acc[0][3].w = fmaf(a, w3.w, acc[0][3].w);
        acc[1][0].x = fmaf(c, w0.x, acc[1][0].x); acc[1][0].y = fmaf(c, w0.y, acc[1][0].y);
        acc[1][0].z = fmaf(c, w0.z, acc[1][0].z); acc[1][0].w = fmaf(c, w0.w, acc[1][0].w);
        acc[1][1].x = fmaf(c, w1.x, acc[1][1].x); acc[1][1].y = fmaf(c, w1.y, acc[1][1].y);
        acc[1][1].z = fmaf(c, w1.z, acc[1][1].z); acc[1][1].w = fmaf(c, w1.w, acc[1][1].w);
        acc[1][2].x = fmaf(c, w2.x, acc[1][2].x); acc[1][2].y = fmaf(c, w2.y, acc[1][2].y);
        acc[1][2].z = fmaf(c, w2.z, acc[1][2].z); acc[1][2].w = fmaf(c, w2.w, acc[1][2].w);
        acc[1][3].x = fmaf(c, w3.x, acc[1][3].x); acc[1][3].y = fmaf(c, w3.y, acc[1][3].y);
        acc[1][3].z = fmaf(c, w3.z, acc[1][3].z); acc[1][3].w = fmaf(c, w3.w, acc[1][3].w);
      }
      if (k4 < 15) { hc0 = hn0; hc1 = hn1; }
    }
  }

  int m0 = node0 + ns, m1 = node0 + ns + 64;
  if (m0 < N) {
    float4* o4 = (float4*)&out[(size_t)m0 * OUT + og];
    o4[0] = acc[0][0]; o4[1] = acc[0][1]; o4[2] = acc[0][2]; o4[3] = acc[0][3];
  }
  if (m1 < N) {
    float4* o4 = (float4*)&out[(size_t)m1 * OUT + og];
    o4[0] = acc[1][0]; o4[1] = acc[1][1]; o4[2] = acc[1][2]; o4[3] = acc[1][3];
  }
}

extern "C" void kernel_launch(void* const* d_in, const int* in_sizes, int n_in,
                              void* d_out, int out_size, void* d_ws, size_t ws_size,
                              hipStream_t stream) {
  const float* x    = (const float*)d_in[0];
  const int*   erow = (const int*)d_in[1];
  const int*   ecol = (const int*)d_in[2];
  const float* eval = (const float*)d_in[3];
  const float* W    = (const float*)d_in[4];
  const float* b    = (const float*)d_in[5];
  float* out = (float*)d_out;

  int N = in_sizes[0] / F;
  int E = in_sizes[1];
  size_t SZ = (size_t)N * F * sizeof(float);
  int ncb = ((N - 1) >> CB_SHIFT) + 1;          // col-blocks (7 for N=50000)
  int B = N * ncb;                              // buckets
  int nScanBlocks = (B + SCAN_ELEMS - 1) / SCAN_ELEMS;
  int rpp = (N + NPART - 1) / NPART;

  char* p = (char*)d_ws;
  float*  hA     = (float*)p;  p += SZ;
  float*  hB     = (float*)p;  p += SZ;
  float2* recs   = (float2*)p; p += (size_t)E * sizeof(float2);
  int*    counts = (int*)p;    p += (size_t)B * sizeof(int);
  int*    offs   = (int*)p;    p += (size_t)(B + 1) * sizeof(int);
  int*    cursor = (int*)p;    p += (size_t)B * sizeof(int);
  int*    bsums  = (int*)p;    p += (size_t)nScanBlocks * sizeof(int);

  int egrid = (E + 255) / 256;
  int g16grid = ((size_t)N * 16 + 255) / 256;
  int ggrid = (N + 127) / 128;

  // --- bucketed CSR build ---
  hipMemsetAsync(counts, 0, (size_t)B * sizeof(int), stream);
  count_part<<<egrid * NPART, 256, 0, stream>>>(erow, ecol, counts, E, rpp, ncb);
  block_scan<<<nScanBlocks, 256, 0, stream>>>(counts, offs, bsums, B);
  scan_sums<<<1, 64, 0, stream>>>(bsums, nScanBlocks);
  add_offsets<<<(B + 255) / 256, 256, 0, stream>>>(offs, bsums, cursor, B, E);
  scatter_part<<<egrid * NPART, 256, 0, stream>>>(erow, ecol, eval, cursor, recs, E, rpp, ncb);

  // --- propagation (h3 -> d_out as scratch) ---
  spmm_g16<<<g16grid, 256, 0, stream>>>(offs, recs, x, hA, N, ncb);    // h1
  spmm_g16<<<g16grid, 256, 0, stream>>>(offs, recs, hA, hB, N, ncb);   // h2
  spmm_g16<<<g16grid, 256, 0, stream>>>(offs, recs, hB, out, N, ncb);  // h3

  gemm_fused4_v5<<<ggrid, 256, 0, stream>>>(x, hA, hB, W, b, out, N);
}